// Round 9
// baseline (125.136 us; speedup 1.0000x reference)
//
#include <hip/hip_runtime.h>
#include <math.h>

#define B_ 4096
#define T_ 64
#define E_ 256
#define H_ 64
#define V_ 32000
#define THREADS 256

typedef __attribute__((ext_vector_type(8))) short bf16x8;
typedef __attribute__((ext_vector_type(4))) float f32x4;
typedef __attribute__((ext_vector_type(4))) unsigned int u32x4;

__device__ __forceinline__ short f2bf(float x) {
    unsigned u = __float_as_uint(x);
    return (short)((u + 0x7FFFu + ((u >> 16) & 1u)) >> 16);
}
__device__ __forceinline__ unsigned cvt_pk_bf16(float lo, float hi) {
    unsigned r;
    asm("v_cvt_pk_bf16_f32 %0, %1, %2" : "=v"(r) : "v"(lo), "v"(hi));
    return r;
}
__device__ __forceinline__ float exp2_raw(float x) {
    float r; asm("v_exp_f32 %0, %1" : "=v"(r) : "v"(x)); return r;
}
__device__ __forceinline__ float rcp_raw(float x) {
    float r; asm("v_rcp_f32 %0, %1" : "=v"(r) : "v"(x)); return r;
}
#define LOG2E 1.442695041f

__device__ __forceinline__ void gld16(const void* g, void* l) {
    __builtin_amdgcn_global_load_lds(
        (const __attribute__((address_space(1))) void*)g,
        (__attribute__((address_space(3))) void*)l, 16, 0, 0);
}

// ---------------------------------------------------------------------------
// Prep (wih_frag layout identical to R4-R8, verified):
//  wih_frag[((vv*2+tl)*8 + kc)*512 + lane*8 + jj]:
//    gate g = tl*128 + (lane&1)*64 + vv*8 + ((lane&15)>>1)
//    k      = kc*32 + (lane>>4)*8 + jj
//  whh_g: bf16 [g][k] row-major;  bias_f = b_ih + b_hh
//  emb_bf: whole table bf16 (RNE) for global_load_lds staging.
// ---------------------------------------------------------------------------
__global__ void prep_kernel(const float* __restrict__ W_ih,
                            const float* __restrict__ W_hh,
                            const float* __restrict__ b_ih,
                            const float* __restrict__ b_hh,
                            const float* __restrict__ emb_table,
                            short* __restrict__ wih_frag,
                            short* __restrict__ whh_g,
                            float* __restrict__ bias_f,
                            short* __restrict__ emb_bf,
                            int tabN) {
    int tid = blockIdx.x * blockDim.x + threadIdx.x;
    int stride = gridDim.x * blockDim.x;
    for (int i = tid; i < 65536; i += stride) {
        int jj = i & 7;
        int l  = (i >> 3) & 63;
        int kc = (i >> 9) & 7;
        int tl = (i >> 12) & 1;
        int vv = i >> 13;
        int uu = (l & 15) >> 1, pp = l & 1;
        int g = tl * 128 + pp * 64 + vv * 8 + uu;
        int k = kc * 32 + (l >> 4) * 8 + jj;
        wih_frag[i] = f2bf(W_ih[g * E_ + k]);
    }
    for (int i = tid; i < 256 * 64; i += stride) whh_g[i] = f2bf(W_hh[i]);
    for (int i = tid; i < 256; i += stride) bias_f[i] = b_ih[i] + b_hh[i];
    for (int i = tid; i < (tabN >> 2); i += stride) {
        float4 v = ((const float4*)emb_table)[i];
        uint2 w;
        w.x = cvt_pk_bf16(v.x, v.y);
        w.y = cvt_pk_bf16(v.z, v.w);
        ((uint2*)emb_bf)[i] = w;
    }
}

// ---------------------------------------------------------------------------
// Wide-wave fused MFMA LSTM. BB=8 rows/block, 256 threads (4 waves),
// grid 512 -> 2 blocks/CU (two independent barrier convoys per CU),
// pinned waves_per_eu(2,2) -> 256-VGPR budget.
// Wave w owns vv = {w, w+4}: 4 gate tiles (128 gate cols of 256 per... 64
// cols), W_ih 32 frags (128 VGPR) + W_hh 8 frags (32 VGPR) register-resident.
// The 8 emb fragment reads/step are SHARED across the wave's 4 tiles
// (halves per-CU LDS traffic vs R8).
// BB=8 trick: MFMA A-slots m=8..15 duplicate rows 0..7 (gather source uses
// tok[m&7]), so D rows 8..15 are valid duplicates -> the R8 packed h-write
// covers the duplicate h slots with the same code; only c4<2 lanes write out.
// Staging: 2 global_load_lds dwordx4 per wave per step from the bf16 table,
// prefetch distance 2 (clamped at tail), 4-deep LDS ring. Counted-vmcnt raw
// barriers keep them in flight: s_waitcnt vmcnt(2) lgkmcnt(0); s_barrier.
// Gates: raw v_exp/v_rcp sigmoid (4 ops), proven parity-interleave exchange.
// ---------------------------------------------------------------------------
template <int TAB>
__global__ __attribute__((amdgpu_flat_work_group_size(THREADS, THREADS),
                          amdgpu_waves_per_eu(2, 2)))
void lstm_w64(const int* __restrict__ x,
              const float* __restrict__ embf,
              const short* __restrict__ embb,
              const short* __restrict__ wih_frag,
              const short* __restrict__ whh_g,
              const float* __restrict__ bias_f,
              float* __restrict__ out) {
    __shared__ __align__(16) short s_ef[4][4096];   // 4-ring emb, 8 KB each
    __shared__ __align__(16) short s_hf[2][1024];   // 2-ring h, 2 KB each
    __shared__ int s_idx[512];                      // [t][m8]

    const int tid  = threadIdx.x;
    const int lane = tid & 63;
    const int wave = tid >> 6;
    const int r0   = blockIdx.x * 8;

    // s_idx[t*8+m] = x[(r0+m)*T + t]
    s_idx[tid]       = x[(r0 + (tid & 7)) * T_ + (tid >> 3)];
    s_idx[tid + 256] = x[(r0 + (tid & 7)) * T_ + ((tid + 256) >> 3)];
    ((u32x4*)s_hf)[tid] = (u32x4){0u, 0u, 0u, 0u};   // zero both h bufs (4 KB)

    const int p  = lane & 1;
    const int c4 = lane >> 4;
    const int u  = (lane & 15) >> 1;
    const int m0 = c4 * 4 + p * 2;
    const float scl2 = p ? 1.0f : 2.0f;
    const float offB = p ? 0.0f : -1.0f;
    const float enB  = -LOG2E * scl2;

    // ---- register-resident weights: vv = wave, wave+4 ----
    bf16x8 wA[2][8], wB[2][8], qA0[2], qA1[2], qB0[2], qB1[2];
    float bA[2], bB[2];
    int hw_s[2];
    #pragma unroll
    for (int t2 = 0; t2 < 2; ++t2) {
        const int vv = wave + t2 * 4;
        const short* wp = wih_frag + vv * 8192 + lane * 8;
        #pragma unroll
        for (int kc = 0; kc < 8; ++kc) {
            wA[t2][kc] = *(const bf16x8*)(wp + kc * 512);
            wB[t2][kc] = *(const bf16x8*)(wp + 4096 + kc * 512);
        }
        const int gA = p * 64 + vv * 8 + u;
        const short* qp = whh_g + gA * 64 + c4 * 8;
        qA0[t2] = *(const bf16x8*)(qp);
        qA1[t2] = *(const bf16x8*)(qp + 32);
        qB0[t2] = *(const bf16x8*)(qp + 8192);
        qB1[t2] = *(const bf16x8*)(qp + 8192 + 32);
        bA[t2] = bias_f[gA];
        bB[t2] = bias_f[gA + 128];
        hw_s[t2] = (vv >> 2) * 512 + (vv & 3) * 128
                 + ((u & 1) ? (m0 + 1) * 8 + (u - 1) : m0 * 8 + u);
    }

    // stage mapping: wave owns chunks kc0, kc1; lane slot = (row dup, k-sub)
    const int kc0  = wave * 2;
    const int kc1  = wave * 2 + 1;
    const int rowl = lane & 7;           // duplicated row source
    const int csub = (lane >> 4) * 8;    // k-sub within chunk

    auto stage_cvt = [&](int tt, int b) {   // TAB=0 fallback staging
        int tok = s_idx[tt * 8 + rowl];
        const float* pr = embf + (size_t)tok * E_;
        #pragma unroll
        for (int kk = 0; kk < 2; ++kk) {
            int kc = kc0 + kk;
            const float* q = pr + kc * 32 + csub;
            float4 f0 = *(const float4*)q;
            float4 f1 = *(const float4*)(q + 4);
            u32x4 w;
            w[0] = cvt_pk_bf16(f0.x, f0.y);
            w[1] = cvt_pk_bf16(f0.z, f0.w);
            w[2] = cvt_pk_bf16(f1.x, f1.y);
            w[3] = cvt_pk_bf16(f1.z, f1.w);
            *(u32x4*)(&s_ef[b][kc * 512] + lane * 8) = w;
        }
    };

    __syncthreads();   // s_idx + zero h visible

    // ---- prologue: stage emb(0)->buf0, emb(1)->buf1 ----
    if (TAB) {
        #pragma unroll
        for (int tt = 0; tt < 2; ++tt) {
            int tok = s_idx[tt * 8 + rowl];
            gld16(embb + (size_t)tok * E_ + kc0 * 32 + csub, &s_ef[tt][kc0 * 512]);
            gld16(embb + (size_t)tok * E_ + kc1 * 32 + csub, &s_ef[tt][kc1 * 512]);
        }
        asm volatile("s_waitcnt vmcnt(0)" ::: "memory");
        asm volatile("s_barrier" ::: "memory");
    } else {
        stage_cvt(0, 0);
        stage_cvt(1, 1);
        __syncthreads();
    }

    float c0[2] = {0.f, 0.f}, c1[2] = {0.f, 0.f};
    float h0v[2] = {0.f, 0.f}, h1v[2] = {0.f, 0.f};

    #pragma unroll 4
    for (int t = 0; t < T_; ++t) {
        // ---- stage emb(t+2) (clamped; uniform vmcnt counting) ----
        {
            const int ts = (t + 2 < T_) ? t + 2 : T_ - 1;
            const int b  = (t + 2) & 3;
            if (TAB) {
                int tok = s_idx[ts * 8 + rowl];
                gld16(embb + (size_t)tok * E_ + kc0 * 32 + csub, &s_ef[b][kc0 * 512]);
                gld16(embb + (size_t)tok * E_ + kc1 * 32 + csub, &s_ef[b][kc1 * 512]);
            } else {
                stage_cvt(ts, b);
            }
        }

        // ---- G = bias + emb(t)*Wih + h(t-1)*Whh  (4 acc chains) ----
        f32x4 pA[2], pB[2];
        #pragma unroll
        for (int t2 = 0; t2 < 2; ++t2) {
            pA[t2] = (f32x4){bA[t2], bA[t2], bA[t2], bA[t2]};
            pB[t2] = (f32x4){bB[t2], bB[t2], bB[t2], bB[t2]};
        }
        const short* eb = &s_ef[t & 3][0] + lane * 8;
        #pragma unroll
        for (int kc = 0; kc < 8; ++kc) {
            bf16x8 av = *(const bf16x8*)(eb + kc * 512);
            pA[0] = __builtin_amdgcn_mfma_f32_16x16x32_bf16(av, wA[0][kc], pA[0], 0, 0, 0);
            pB[0] = __builtin_amdgcn_mfma_f32_16x16x32_bf16(av, wB[0][kc], pB[0], 0, 0, 0);
            pA[1] = __builtin_amdgcn_mfma_f32_16x16x32_bf16(av, wA[1][kc], pA[1], 0, 0, 0);
            pB[1] = __builtin_amdgcn_mfma_f32_16x16x32_bf16(av, wB[1][kc], pB[1], 0, 0, 0);
        }
        const short* hb = &s_hf[t & 1][0] + lane * 8;
        bf16x8 hv0 = *(const bf16x8*)(hb);
        bf16x8 hv1 = *(const bf16x8*)(hb + 512);
        #pragma unroll
        for (int t2 = 0; t2 < 2; ++t2) {
            pA[t2] = __builtin_amdgcn_mfma_f32_16x16x32_bf16(hv0, qA0[t2], pA[t2], 0, 0, 0);
            pA[t2] = __builtin_amdgcn_mfma_f32_16x16x32_bf16(hv1, qA1[t2], pA[t2], 0, 0, 0);
            pB[t2] = __builtin_amdgcn_mfma_f32_16x16x32_bf16(hv0, qB0[t2], pB[t2], 0, 0, 0);
            pB[t2] = __builtin_amdgcn_mfma_f32_16x16x32_bf16(hv1, qB1[t2], pB[t2], 0, 0, 0);
        }

        // ---- gates (fast exp2/rcp; proven parity interleave) ----
        #pragma unroll
        for (int t2 = 0; t2 < 2; ++t2) {
            float sA[4], Bv[4];
            #pragma unroll
            for (int q = 0; q < 4; ++q) {
                sA[q] = rcp_raw(1.0f + exp2_raw(-LOG2E * pA[t2][q]));      // sigm(i)|sigm(f)
                Bv[q] = rcp_raw(1.0f + exp2_raw(enB * pB[t2][q])) * scl2 + offB; // tanh(g)|sigm(o)
            }
            float s1 = p ? sA[0] : sA[2] * Bv[2];
            float r1 = __shfl_xor(s1, 1);
            float s2 = p ? sA[1] : sA[3] * Bv[3];
            float r2 = __shfl_xor(s2, 1);
            float r3 = __shfl_xor(Bv[0], 1);
            float r4 = __shfl_xor(Bv[1], 1);
            float fc0 = p ? sA[2] : r1;
            float ic0 = p ? r1 : sA[0] * Bv[0];
            float oc0 = p ? Bv[2] : r3;
            float fc1 = p ? sA[3] : r2;
            float ic1 = p ? r2 : sA[1] * Bv[1];
            float oc1 = p ? Bv[3] : r4;
            c0[t2] = fc0 * c0[t2] + ic0;
            c1[t2] = fc1 * c1[t2] + ic1;
            h0v[t2] = oc0 * (1.0f - 2.0f * rcp_raw(1.0f + exp2_raw(2.0f * LOG2E * c0[t2])));
            h1v[t2] = oc1 * (1.0f - 2.0f * rcp_raw(1.0f + exp2_raw(2.0f * LOG2E * c1[t2])));

            float snd = (u & 1) ? h0v[t2] : h1v[t2];
            float rcv = __shfl_xor(snd, 2);
            unsigned hw = (u & 1) ? cvt_pk_bf16(rcv, h1v[t2]) : cvt_pk_bf16(h0v[t2], rcv);
            *(unsigned*)(&s_hf[(t + 1) & 1][0] + hw_s[t2]) = hw;
        }

        // ---- tail: counted vmcnt (stage t+2 stays in flight) ----
        if (TAB) {
            asm volatile("s_waitcnt vmcnt(2) lgkmcnt(0)" ::: "memory");
            asm volatile("s_barrier" ::: "memory");
        } else {
            __syncthreads();
        }
    }

    if (c4 < 2) {
        #pragma unroll
        for (int t2 = 0; t2 < 2; ++t2) {
            const int j = (wave + t2 * 4) * 8 + u;
            out[(r0 + m0) * H_ + j]     = h0v[t2];
            out[(r0 + m0 + 1) * H_ + j] = h1v[t2];
        }
    }
}

// ---------------------------------------------------------------------------
extern "C" void kernel_launch(void* const* d_in, const int* in_sizes, int n_in,
                              void* d_out, int out_size, void* d_ws, size_t ws_size,
                              hipStream_t stream) {
    const int*   x         = (const int*)d_in[0];
    const float* emb_table = (const float*)d_in[1];
    const float* W_ih      = (const float*)d_in[2];
    const float* W_hh      = (const float*)d_in[3];
    const float* b_ih      = (const float*)d_in[4];
    const float* b_hh      = (const float*)d_in[5];
    float*       out       = (float*)d_out;

    short* wih_frag = (short*)d_ws;               // 65536 shorts (128 KB)
    short* whh_g    = wih_frag + 65536;           // 16384 shorts (32 KB)
    float* bias_f   = (float*)(whh_g + 16384);    // 256 floats (1 KB)
    short* emb_bf   = (short*)(bias_f + 256);     // 8.192M shorts (16.4 MB)

    const size_t need = (size_t)(65536 + 16384) * 2 + 256 * 4
                      + (size_t)V_ * E_ * 2;
    const int tab = (ws_size >= need) ? 1 : 0;

    prep_kernel<<<tab ? 1024 : 64, 256, 0, stream>>>(
        W_ih, W_hh, b_ih, b_hh, emb_table,
        wih_frag, whh_g, bias_f,
        tab ? emb_bf : wih_frag, tab ? V_ * E_ : 0);

    if (tab) {
        lstm_w64<1><<<B_ / 8, THREADS, 0, stream>>>(
            x, emb_table, emb_bf, wih_frag, whh_g, bias_f, out);
    } else {
        lstm_w64<0><<<B_ / 8, THREADS, 0, stream>>>(
            x, emb_table, wih_frag, wih_frag, whh_g, bias_f, out);
    }
}

// Round 10
// 75.049 us; speedup vs baseline: 1.6674x; 1.6674x over previous
//
#include <hip/hip_runtime.h>
#include <math.h>

#define B_ 4096
#define T_ 64
#define E_ 256
#define H_ 64
#define V_ 32000
#define THREADS 1024

typedef __attribute__((ext_vector_type(8))) short bf16x8;
typedef __attribute__((ext_vector_type(4))) float f32x4;
typedef __attribute__((ext_vector_type(4))) unsigned int u32x4;

__device__ __forceinline__ short f2bf(float x) {
    unsigned u = __float_as_uint(x);
    return (short)((u + 0x7FFFu + ((u >> 16) & 1u)) >> 16);
}
__device__ __forceinline__ unsigned cvt_pk_bf16(float lo, float hi) {
    unsigned r;
    asm("v_cvt_pk_bf16_f32 %0, %1, %2" : "=v"(r) : "v"(lo), "v"(hi));
    return r;
}
__device__ __forceinline__ float exp2_raw(float x) {
    float r; asm("v_exp_f32 %0, %1" : "=v"(r) : "v"(x)); return r;
}
__device__ __forceinline__ float rcp_raw(float x) {
    float r; asm("v_rcp_f32 %0, %1" : "=v"(r) : "v"(x)); return r;
}
#define LOG2E 1.442695041f

__device__ __forceinline__ void gld16(const void* g, void* l) {
    __builtin_amdgcn_global_load_lds(
        (const __attribute__((address_space(1))) void*)g,
        (__attribute__((address_space(3))) void*)l, 16, 0, 0);
}

// ---------------------------------------------------------------------------
// Prep (wih_frag layout identical to R4-R9, verified):
//  wih_frag[((vv*2+tl)*8 + kc)*512 + lane*8 + jj]:
//    gate g = tl*128 + (lane&1)*64 + vv*8 + ((lane&15)>>1)
//    k      = kc*32 + (lane>>4)*8 + jj
//  whh_g: bf16 [g][k] row-major;  bias_f = b_ih + b_hh
//  emb_bf: whole table bf16 (RNE) for global_load_lds staging.
// ---------------------------------------------------------------------------
__global__ void prep_kernel(const float* __restrict__ W_ih,
                            const float* __restrict__ W_hh,
                            const float* __restrict__ b_ih,
                            const float* __restrict__ b_hh,
                            const float* __restrict__ emb_table,
                            short* __restrict__ wih_frag,
                            short* __restrict__ whh_g,
                            float* __restrict__ bias_f,
                            short* __restrict__ emb_bf,
                            int tabN) {
    int tid = blockIdx.x * blockDim.x + threadIdx.x;
    int stride = gridDim.x * blockDim.x;
    for (int i = tid; i < 65536; i += stride) {
        int jj = i & 7;
        int l  = (i >> 3) & 63;
        int kc = (i >> 9) & 7;
        int tl = (i >> 12) & 1;
        int vv = i >> 13;
        int uu = (l & 15) >> 1, pp = l & 1;
        int g = tl * 128 + pp * 64 + vv * 8 + uu;
        int k = kc * 32 + (l >> 4) * 8 + jj;
        wih_frag[i] = f2bf(W_ih[g * E_ + k]);
    }
    for (int i = tid; i < 256 * 64; i += stride) whh_g[i] = f2bf(W_hh[i]);
    for (int i = tid; i < 256; i += stride) bias_f[i] = b_ih[i] + b_hh[i];
    for (int i = tid; i < (tabN >> 2); i += stride) {
        float4 v = ((const float4*)emb_table)[i];
        uint2 w;
        w.x = cvt_pk_bf16(v.x, v.y);
        w.y = cvt_pk_bf16(v.z, v.w);
        ((uint2*)emb_bf)[i] = w;
    }
}

// ---------------------------------------------------------------------------
// Fused MFMA LSTM (R7 structure, 87us baseline) + fast gates + gld16 staging.
// grid 256 (1 block/CU), 1024 threads = 16 waves, pinned 4 waves/EU.
//  waves 0-7  (compute): wave w owns vv=w (tiles A=i/f, B=g/o). W_ih (64
//       VGPR) + W_hh (16 VGPR) register-resident. Per step: R-phase (h MFMA
//       + in-register gates via raw v_exp/v_rcp + packed h write), then
//       P(t+1) = bias + emb(t+1)*W_ih (8 ds_read_b128 + 16 MFMA).
//  waves 8-15 (stage): wave 8+s stages fragment chunk kc=s of emb(t+2) into
//       the 4-deep LDS ring with ONE global_load_lds dwordx4 from the bf16
//       table (per-lane gather src, linear LDS dest == fragment layout).
// Fragment LDS layout (zero-conflict): chunk (kc,lane) at kc*1024B + lane*16B
//   holds A[m=lane&15][k=kc*32+(lane>>4)*8+jj].
// One __syncthreads per step (drains the stage gld16; distance-2 prefetch).
// ---------------------------------------------------------------------------
template <int TAB>
__global__ __attribute__((amdgpu_flat_work_group_size(THREADS, THREADS),
                          amdgpu_waves_per_eu(4, 4)))
void lstm_f(const int* __restrict__ x,
            const float* __restrict__ embf,
            const short* __restrict__ embb,
            const short* __restrict__ wih_frag,
            const short* __restrict__ whh_g,
            const float* __restrict__ bias_f,
            float* __restrict__ out) {
    __shared__ __align__(16) short s_ef[4][4096];   // 4-ring emb, 8 KB each
    __shared__ __align__(16) short s_hf[2][1024];   // 2-ring h, 2 KB each
    __shared__ int s_idx[1024];                     // [t][m]

    const int tid  = threadIdx.x;
    const int lane = tid & 63;
    const int wave = tid >> 6;
    const int r0   = blockIdx.x * 16;

    // idx: s_idx[t*16+m] = x[(r0+m)*T + t]; zero h ring
    s_idx[(tid & 63) * 16 + (tid >> 6)] = x[(r0 + (tid >> 6)) * T_ + (tid & 63)];
    ((int*)s_hf)[tid] = 0;

    const int p  = lane & 1;
    const int c4 = lane >> 4;
    const int u  = (lane & 15) >> 1;
    const float scl2 = p ? 1.0f : 2.0f;
    const float offB = p ? 0.0f : -1.0f;
    const float enB  = -LOG2E * scl2;
    const int m0 = c4 * 4 + p * 2;

    // ---- compute-wave setup ----
    bf16x8 wA[8], wB[8], qA0, qA1, qB0, qB1;
    float bA = 0.f, bB = 0.f;
    int hw_s = 0;
    if (wave < 8) {
        const short* wp = wih_frag + wave * 8192 + lane * 8;
        #pragma unroll
        for (int kc = 0; kc < 8; ++kc) {
            wA[kc] = *(const bf16x8*)(wp + kc * 512);
            wB[kc] = *(const bf16x8*)(wp + 4096 + kc * 512);
        }
        const int gA = p * 64 + wave * 8 + u;
        const short* qp = whh_g + gA * 64 + c4 * 8;
        qA0 = *(const bf16x8*)(qp);
        qA1 = *(const bf16x8*)(qp + 32);
        qB0 = *(const bf16x8*)(qp + 8192);
        qB1 = *(const bf16x8*)(qp + 8192 + 32);
        bA = bias_f[gA];
        bB = bias_f[gA + 128];
        hw_s = (wave >> 2) * 512 + (wave & 3) * 128
             + ((u & 1) ? (m0 + 1) * 8 + (u - 1) : m0 * 8 + u);
    }

    // ---- stage-wave mapping: wave 8+s owns chunk kc=s ----
    const int m16   = lane & 15;
    const int sbase = (wave - 8) * 512 + lane * 8;                 // shorts
    const int skoff = (wave - 8) * 32 + (lane >> 4) * 8;           // emb col

    __syncthreads();   // s_idx, h=0 visible

    if (wave >= 8) {
        // prologue: direct-stage t=0 -> buf0, t=1 -> buf1
        #pragma unroll
        for (int tt = 0; tt < 2; ++tt) {
            int tok = s_idx[tt * 16 + m16];
            if (TAB) {
                gld16(embb + (size_t)tok * E_ + skoff,
                      &s_ef[tt][(wave - 8) * 512]);
            } else {
                const float* pr = embf + (size_t)tok * E_ + skoff;
                float4 f0 = *(const float4*)pr;
                float4 f1 = *(const float4*)(pr + 4);
                u32x4 w;
                w[0] = cvt_pk_bf16(f0.x, f0.y);
                w[1] = cvt_pk_bf16(f0.z, f0.w);
                w[2] = cvt_pk_bf16(f1.x, f1.y);
                w[3] = cvt_pk_bf16(f1.z, f1.w);
                *(u32x4*)(&s_ef[tt][0] + sbase) = w;
            }
        }
    }
    __syncthreads();   // buf0, buf1 staged

    // ---- compute prologue: pre-gates P(0) from buf0 ----
    f32x4 pA, pB;
    if (wave < 8) {
        pA = (f32x4){bA, bA, bA, bA};
        pB = (f32x4){bB, bB, bB, bB};
        const short* eb = &s_ef[0][0] + lane * 8;
        #pragma unroll
        for (int kc = 0; kc < 8; ++kc) {
            bf16x8 av = *(const bf16x8*)(eb + kc * 512);
            pA = __builtin_amdgcn_mfma_f32_16x16x32_bf16(av, wA[kc], pA, 0, 0, 0);
            pB = __builtin_amdgcn_mfma_f32_16x16x32_bf16(av, wB[kc], pB, 0, 0, 0);
        }
    }

    float c0 = 0.f, c1 = 0.f, h0v = 0.f, h1v = 0.f;

    #pragma unroll 4
    for (int t = 0; t < T_; ++t) {
        if (wave < 8) {
            // ---- R: G(t) = preG + h(t-1)*Whh ----
            const short* hb = &s_hf[t & 1][0] + lane * 8;
            bf16x8 hv0 = *(const bf16x8*)(hb);
            bf16x8 hv1 = *(const bf16x8*)(hb + 512);
            pA = __builtin_amdgcn_mfma_f32_16x16x32_bf16(hv0, qA0, pA, 0, 0, 0);
            pA = __builtin_amdgcn_mfma_f32_16x16x32_bf16(hv1, qA1, pA, 0, 0, 0);
            pB = __builtin_amdgcn_mfma_f32_16x16x32_bf16(hv0, qB0, pB, 0, 0, 0);
            pB = __builtin_amdgcn_mfma_f32_16x16x32_bf16(hv1, qB1, pB, 0, 0, 0);

            // ---- gates (raw v_exp/v_rcp; proven parity interleave) ----
            float sA[4], Bv[4];
            #pragma unroll
            for (int q = 0; q < 4; ++q) {
                sA[q] = rcp_raw(1.0f + exp2_raw(-LOG2E * pA[q]));        // sigm(i)|sigm(f)
                Bv[q] = rcp_raw(1.0f + exp2_raw(enB * pB[q])) * scl2 + offB; // tanh(g)|sigm(o)
            }
            float s1 = p ? sA[0] : sA[2] * Bv[2];
            float r1 = __shfl_xor(s1, 1);
            float s2 = p ? sA[1] : sA[3] * Bv[3];
            float r2 = __shfl_xor(s2, 1);
            float r3 = __shfl_xor(Bv[0], 1);
            float r4 = __shfl_xor(Bv[1], 1);
            float fc0 = p ? sA[2] : r1;
            float ic0 = p ? r1 : sA[0] * Bv[0];
            float oc0 = p ? Bv[2] : r3;
            float fc1 = p ? sA[3] : r2;
            float ic1 = p ? r2 : sA[1] * Bv[1];
            float oc1 = p ? Bv[3] : r4;
            c0 = fc0 * c0 + ic0;
            c1 = fc1 * c1 + ic1;
            h0v = oc0 * (1.0f - 2.0f * rcp_raw(1.0f + exp2_raw(2.0f * LOG2E * c0)));
            h1v = oc1 * (1.0f - 2.0f * rcp_raw(1.0f + exp2_raw(2.0f * LOG2E * c1)));

            // packed b32 h-write (column-pair via lane^2 exchange, cvt_pk)
            float snd = (u & 1) ? h0v : h1v;
            float rcv = __shfl_xor(snd, 2);
            unsigned hw = (u & 1) ? cvt_pk_bf16(rcv, h1v) : cvt_pk_bf16(h0v, rcv);
            *(unsigned*)(&s_hf[(t + 1) & 1][0] + hw_s) = hw;

            // ---- P: preG(t+1) = bias + emb(t+1)*Wih ----
            if (t < T_ - 1) {
                pA = (f32x4){bA, bA, bA, bA};
                pB = (f32x4){bB, bB, bB, bB};
                const short* eb = &s_ef[(t + 1) & 3][0] + lane * 8;
                #pragma unroll
                for (int kc = 0; kc < 8; ++kc) {
                    bf16x8 av = *(const bf16x8*)(eb + kc * 512);
                    pA = __builtin_amdgcn_mfma_f32_16x16x32_bf16(av, wA[kc], pA, 0, 0, 0);
                    pB = __builtin_amdgcn_mfma_f32_16x16x32_bf16(av, wB[kc], pB, 0, 0, 0);
                }
            }
        } else {
            // ---- stage emb(t+2) into ring buf (t+2)&3 ----
            if (t + 2 < T_) {
                int tok = s_idx[(t + 2) * 16 + m16];
                if (TAB) {
                    gld16(embb + (size_t)tok * E_ + skoff,
                          &s_ef[(t + 2) & 3][(wave - 8) * 512]);
                } else {
                    const float* pr = embf + (size_t)tok * E_ + skoff;
                    float4 f0 = *(const float4*)pr;
                    float4 f1 = *(const float4*)(pr + 4);
                    u32x4 w;
                    w[0] = cvt_pk_bf16(f0.x, f0.y);
                    w[1] = cvt_pk_bf16(f0.z, f0.w);
                    w[2] = cvt_pk_bf16(f1.x, f1.y);
                    w[3] = cvt_pk_bf16(f1.z, f1.w);
                    *(u32x4*)(&s_ef[(t + 2) & 3][0] + sbase) = w;
                }
            }
        }
        __syncthreads();
    }

    if (wave < 8) {
        const int j = wave * 8 + u;
        out[(r0 + m0) * H_ + j]     = h0v;
        out[(r0 + m0 + 1) * H_ + j] = h1v;
    }
}

// ---------------------------------------------------------------------------
extern "C" void kernel_launch(void* const* d_in, const int* in_sizes, int n_in,
                              void* d_out, int out_size, void* d_ws, size_t ws_size,
                              hipStream_t stream) {
    const int*   x         = (const int*)d_in[0];
    const float* emb_table = (const float*)d_in[1];
    const float* W_ih      = (const float*)d_in[2];
    const float* W_hh      = (const float*)d_in[3];
    const float* b_ih      = (const float*)d_in[4];
    const float* b_hh      = (const float*)d_in[5];
    float*       out       = (float*)d_out;

    short* wih_frag = (short*)d_ws;               // 65536 shorts (128 KB)
    short* whh_g    = wih_frag + 65536;           // 16384 shorts (32 KB)
    float* bias_f   = (float*)(whh_g + 16384);    // 256 floats (1 KB)
    short* emb_bf   = (short*)(bias_f + 256);     // 8.192M shorts (16.4 MB)

    const size_t need = (size_t)(65536 + 16384) * 2 + 256 * 4
                      + (size_t)V_ * E_ * 2;
    const int tab = (ws_size >= need) ? 1 : 0;

    prep_kernel<<<tab ? 1024 : 64, 256, 0, stream>>>(
        W_ih, W_hh, b_ih, b_hh, emb_table,
        wih_frag, whh_g, bias_f,
        tab ? emb_bf : wih_frag, tab ? V_ * E_ : 0);

    if (tab) {
        lstm_f<1><<<B_ / 16, THREADS, 0, stream>>>(
            x, emb_table, emb_bf, wih_frag, whh_g, bias_f, out);
    } else {
        lstm_f<0><<<B_ / 16, THREADS, 0, stream>>>(
            x, emb_table, wih_frag, wih_frag, whh_g, bias_f, out);
    }
}